// Round 9
// baseline (378.103 us; speedup 1.0000x reference)
//
#include <hip/hip_runtime.h>
#include <math.h>

#define NB    64        // graphs
#define NPER  1024      // nodes per graph
#define NTOT  65536     // total nodes
#define ETOT  1048576   // edges
#define FEAT  64
#define HID   128
#define KSEL  10
#define MAXDEG 64       // CSR slot capacity per node (max in-degree ~40)

// Pipeline (agg commuted before the weight multiply, dinv folded into gemm output):
//   A = agg(Z)             agg_k  : LDS-staged gather, DUAL-CHAIN ILP (2 nodes/thread,
//                                   8 LDS reads in flight) -> k-octet bf16 hi/lo
//   Z' = relu(A@W+b)*dinv  gemm_k : 64x128 MFMA tile, bf16x3 (hi*hi+hi*lo+lo*hi)
// csrpack_k: per-graph CSR in LDS atomics; NODE-MAJOR col16[node*64+slot] -> ushort4
//   index loads. + pack/part-zero tail blocks (one dispatch).
// R8 post-mortem: agg is LATENCY-bound (43us vs ~12us floor; VALUBusy 24%, HBM 26%),
//   so this round doubles per-thread MLP. launch_bounds(1024,8) keeps VGPR<=64 so
//   2 blocks/CU (32 waves) survive the extra chain.
// NOTE (R6 lesson): do NOT fuse the gather into the GEMM (17x L3 traffic, 1.9 TB/s).

typedef __attribute__((ext_vector_type(8))) short bf16x8;
typedef __attribute__((ext_vector_type(4))) float f32x4;

static __device__ __forceinline__ unsigned short f2bf(float x) {   // RNE fp32->bf16
    unsigned u = __float_as_uint(x);
    return (unsigned short)((u + 0x7FFFu + ((u >> 16) & 1u)) >> 16);
}
static __device__ __forceinline__ float bf2f(unsigned short s) {
    return __uint_as_float(((unsigned)s) << 16);
}

// ------- CSR build (per-graph LDS atomics) + weight-pack + part-zero tail ----------
__global__ __launch_bounds__(1024) void csrpack_k(const int* __restrict__ src,
                                                  const int* __restrict__ dst,
                                                  int* __restrict__ cnt,
                                                  unsigned short* __restrict__ col16,
                                                  const float* __restrict__ W0,
                                                  const float* __restrict__ W1,
                                                  const float* __restrict__ W2,
                                                  unsigned short* __restrict__ Wph,
                                                  unsigned short* __restrict__ Wpl,
                                                  float* __restrict__ part) {
    int t = threadIdx.x;
    int b = blockIdx.x;
    if (b >= NB) {
        int pb = b - NB;
        if (pb == 40) {   // zero atomicMax target (relu>=0 so 0.0f bits are the floor)
            for (int i = t; i < NB * 128; i += 1024) part[i] = 0.f;
            return;
        }
        int idx = pb * 1024 + t;          // 0..40959 covers 320*128
        if (idx >= 320 * 128) return;
        int k = idx >> 7;
        int c = idx & 127;
        float v;
        size_t mb;
        int kk;
        if (k < 64)       { kk = k;       v = W0[kk * 128 + c]; mb = 0; }
        else if (k < 192) { kk = k - 64;  v = W1[kk * 128 + c]; mb = (size_t)64 * 128; }
        else              { kk = k - 192; v = W2[kk * 128 + c]; mb = (size_t)192 * 128; }
        unsigned short h  = f2bf(v);
        unsigned short lo = f2bf(v - bf2f(h));
        size_t d = mb + ((size_t)(kk >> 3) * 128 + c) * 8 + (kk & 7);
        Wph[d] = h;
        Wpl[d] = lo;
        return;
    }
    // per-graph CSR, node-major output
    __shared__ int lcnt[NPER];
    int g = b;
    int gbase = g << 10;
    int ebase = g * (NPER * 16);          // DEG=16, graph-contiguous edge rows
    lcnt[t] = 0;
    __syncthreads();
    const int4* ds4 = (const int4*)(dst + ebase);
    const int4* ss4 = (const int4*)(src + ebase);
#pragma unroll 1
    for (int i = 0; i < 4; ++i) {
        int e4 = i * 1024 + t;            // 4096 int4 groups cover 16384 edges
        int4 dv = ds4[e4];
        int4 sv = ss4[e4];
        int d0 = dv.x & (NPER - 1), s0 = sv.x & (NPER - 1);
        int d1 = dv.y & (NPER - 1), s1 = sv.y & (NPER - 1);
        int d2 = dv.z & (NPER - 1), s2 = sv.z & (NPER - 1);
        int d3 = dv.w & (NPER - 1), s3 = sv.w & (NPER - 1);
        int p0 = atomicAdd(&lcnt[d0], 1);
        col16[(size_t)(gbase + d0) * MAXDEG + p0] = (unsigned short)s0;
        int p1 = atomicAdd(&lcnt[d1], 1);
        col16[(size_t)(gbase + d1) * MAXDEG + p1] = (unsigned short)s1;
        int p2 = atomicAdd(&lcnt[d2], 1);
        col16[(size_t)(gbase + d2) * MAXDEG + p2] = (unsigned short)s2;
        int p3 = atomicAdd(&lcnt[d3], 1);
        col16[(size_t)(gbase + d3) * MAXDEG + p3] = (unsigned short)s3;
    }
    __syncthreads();
    cnt[gbase + t] = lcnt[t];
}

// ---------------- LDS-staged aggregation, dual-chain gather ------------------------
// block=(graph g, chunk c). out_v = dv * sum(staged over {v} u N(v)), split hi/lo.
// If Wf != nullptr, the LAST NB blocks instead compute glob/gproj (fused glob_k).
__global__ __launch_bounds__(1024, 8) void agg_k(const float* __restrict__ Z,
                                                 const float* __restrict__ x,
                                                 const unsigned short* __restrict__ col16,
                                                 const int* __restrict__ cnt,
                                                 unsigned short* __restrict__ Ah,
                                                 unsigned short* __restrict__ Al,
                                                 int cshift,
                                                 float* __restrict__ fvec,
                                                 const float* __restrict__ Wf,
                                                 const float* __restrict__ bfv,
                                                 const float* __restrict__ W2g,
                                                 float* __restrict__ gproj,
                                                 const float* __restrict__ part) {
    __shared__ float4 sy4[4096];   // 64 KB
    int t = threadIdx.x;

    if (Wf && (int)blockIdx.x >= (int)gridDim.x - NB) {   // fused glob block
        float* sm = (float*)sy4;
        float* mp = sm;            // 128
        float* ps = sm + 128;      // 1024
        float* gl = sm + 128 + 1024;
        int gg = blockIdx.x - (gridDim.x - NB);
        int o = t & 127, s8 = t >> 7;       // 8 segments of 16 k each
        if (t < 128) mp[t] = part[(size_t)gg * 128 + t];
        __syncthreads();
        float p = 0.f;
#pragma unroll
        for (int q = 0; q < 16; ++q) { int k = s8 * 16 + q; p += mp[k] * Wf[(size_t)k * 128 + o]; }
        ps[t] = p;
        __syncthreads();
        if (t < 128) {
            float a = bfv[t];
#pragma unroll
            for (int q = 0; q < 8; ++q) a += ps[q * 128 + t];
            gl[t] = a;
        }
        __syncthreads();
        p = 0.f;
#pragma unroll
        for (int q = 0; q < 16; ++q) { int k = s8 * 16 + q; p += gl[k] * W2g[(size_t)(128 + k) * 128 + o]; }
        ps[t] = p;
        __syncthreads();
        if (t < 128) {
            float a = 0.f;
#pragma unroll
            for (int q = 0; q < 8; ++q) a += ps[q * 128 + t];
            gproj[(size_t)gg * 128 + t] = a;
        }
        return;
    }

    int g = blockIdx.x >> cshift;
    int c = blockIdx.x & ((1 << cshift) - 1);
    int gbase = g << 10;

    if (x) {
#pragma unroll
        for (int j = 0; j < 4; ++j) {
            int fl = j * 1024 + t;
            int v = fl >> 2, q = fl & 3;
            float dvv = rsqrtf((float)cnt[gbase + v] + 1.0f);
            float4 z = *(const float4*)&x[(size_t)(gbase + v) * FEAT + c * 16 + q * 4];
            z.x *= dvv; z.y *= dvv; z.z *= dvv; z.w *= dvv;
            sy4[fl] = z;
        }
    } else {
        const float4* Zg4 = (const float4*)(Z + ((size_t)c * NTOT + gbase) * 16);
#pragma unroll
        for (int j = 0; j < 4; ++j) sy4[j * 1024 + t] = Zg4[j * 1024 + t];
    }
    __syncthreads();

    int f4 = t & 3;
    int vl = t >> 2;                        // 0..255
    int krow = c * 16 + f4 * 4;

#pragma unroll 1
    for (int half = 0; half < 2; ++half) {
        int vA = half * 512 + vl;
        int vB = vA + 256;
        int gA = gbase + vA, gB = gbase + vB;
        int nA = cnt[gA], nB = cnt[gB];
        const unsigned short* ipA = col16 + (size_t)gA * MAXDEG;
        const unsigned short* ipB = col16 + (size_t)gB * MAXDEG;
        float4 accA = sy4[vA * 4 + f4];     // self terms
        float4 accB = sy4[vB * 4 + f4];
        int nmin = nA < nB ? nA : nB;
        int i = 0;
        for (; i + 4 <= nmin; i += 4) {     // dual chain: 2 idx loads + 8 LDS reads
            ushort4 sA = *(const ushort4*)&ipA[i];
            ushort4 sB = *(const ushort4*)&ipB[i];
            float4 a0 = sy4[(int)sA.x * 4 + f4];
            float4 a1 = sy4[(int)sA.y * 4 + f4];
            float4 a2 = sy4[(int)sA.z * 4 + f4];
            float4 a3 = sy4[(int)sA.w * 4 + f4];
            float4 b0 = sy4[(int)sB.x * 4 + f4];
            float4 b1 = sy4[(int)sB.y * 4 + f4];
            float4 b2 = sy4[(int)sB.z * 4 + f4];
            float4 b3 = sy4[(int)sB.w * 4 + f4];
            accA.x += (a0.x + a1.x) + (a2.x + a3.x);
            accA.y += (a0.y + a1.y) + (a2.y + a3.y);
            accA.z += (a0.z + a1.z) + (a2.z + a3.z);
            accA.w += (a0.w + a1.w) + (a2.w + a3.w);
            accB.x += (b0.x + b1.x) + (b2.x + b3.x);
            accB.y += (b0.y + b1.y) + (b2.y + b3.y);
            accB.z += (b0.z + b1.z) + (b2.z + b3.z);
            accB.w += (b0.w + b1.w) + (b2.w + b3.w);
        }
        int iB = i;
        for (; i + 4 <= nA; i += 4) {       // A tail, 4-way
            ushort4 sA = *(const ushort4*)&ipA[i];
            float4 a0 = sy4[(int)sA.x * 4 + f4];
            float4 a1 = sy4[(int)sA.y * 4 + f4];
            float4 a2 = sy4[(int)sA.z * 4 + f4];
            float4 a3 = sy4[(int)sA.w * 4 + f4];
            accA.x += (a0.x + a1.x) + (a2.x + a3.x);
            accA.y += (a0.y + a1.y) + (a2.y + a3.y);
            accA.z += (a0.z + a1.z) + (a2.z + a3.z);
            accA.w += (a0.w + a1.w) + (a2.w + a3.w);
        }
        for (; i < nA; ++i) {
            float4 ya = sy4[(int)ipA[i] * 4 + f4];
            accA.x += ya.x; accA.y += ya.y; accA.z += ya.z; accA.w += ya.w;
        }
        for (; iB + 4 <= nB; iB += 4) {     // B tail, 4-way
            ushort4 sB = *(const ushort4*)&ipB[iB];
            float4 b0 = sy4[(int)sB.x * 4 + f4];
            float4 b1 = sy4[(int)sB.y * 4 + f4];
            float4 b2 = sy4[(int)sB.z * 4 + f4];
            float4 b3 = sy4[(int)sB.w * 4 + f4];
            accB.x += (b0.x + b1.x) + (b2.x + b3.x);
            accB.y += (b0.y + b1.y) + (b2.y + b3.y);
            accB.z += (b0.z + b1.z) + (b2.z + b3.z);
            accB.w += (b0.w + b1.w) + (b2.w + b3.w);
        }
        for (; iB < nB; ++iB) {
            float4 yb = sy4[(int)ipB[iB] * 4 + f4];
            accB.x += yb.x; accB.y += yb.y; accB.z += yb.z; accB.w += yb.w;
        }
        float dvA = rsqrtf((float)nA + 1.0f);
        float dvB = rsqrtf((float)nB + 1.0f);
        accA.x *= dvA; accA.y *= dvA; accA.z *= dvA; accA.w *= dvA;
        accB.x *= dvB; accB.y *= dvB; accB.z *= dvB; accB.w *= dvB;
        size_t baA = ((size_t)(krow >> 3) * NTOT + gA) * 8 + (krow & 7);
        size_t baB = ((size_t)(krow >> 3) * NTOT + gB) * 8 + (krow & 7);
        ushort4 h, lo;
        h.x = f2bf(accA.x); lo.x = f2bf(accA.x - bf2f(h.x));
        h.y = f2bf(accA.y); lo.y = f2bf(accA.y - bf2f(h.y));
        h.z = f2bf(accA.z); lo.z = f2bf(accA.z - bf2f(h.z));
        h.w = f2bf(accA.w); lo.w = f2bf(accA.w - bf2f(h.w));
        *(ushort4*)&Ah[baA] = h;
        *(ushort4*)&Al[baA] = lo;
        h.x = f2bf(accB.x); lo.x = f2bf(accB.x - bf2f(h.x));
        h.y = f2bf(accB.y); lo.y = f2bf(accB.y - bf2f(h.y));
        h.z = f2bf(accB.z); lo.z = f2bf(accB.z - bf2f(h.z));
        h.w = f2bf(accB.w); lo.w = f2bf(accB.w - bf2f(h.w));
        *(ushort4*)&Ah[baB] = h;
        *(ushort4*)&Al[baB] = lo;
    }

    if (fvec && c == 0) {   // f_v = dinv_v*(dinv_v + sum dinv_s)
        __syncthreads();
        float* sdv = (float*)sy4;
        float dv = rsqrtf((float)cnt[gbase + t] + 1.0f);
        sdv[t] = dv;
        __syncthreads();
        int n = cnt[gbase + t];
        float acc = dv;
        const unsigned short* ip = col16 + (size_t)(gbase + t) * MAXDEG;
        int i = 0;
        for (; i + 4 <= n; i += 4) {
            ushort4 s4 = *(const ushort4*)&ip[i];
            acc += (sdv[s4.x] + sdv[s4.y]) + (sdv[s4.z] + sdv[s4.w]);
        }
        for (; i < n; ++i) acc += sdv[ip[i]];
        fvec[gbase + t] = dv * acc;
    }
}

// ---------------- bf16x3 MFMA GEMM: 64 rows x 128 cols per block, fused epilogue ----
// Single-shot A staging (whole K, 32 KB hi+lo, ONE barrier), B frags straight from L2.
// A frag: row = lane&15, k-octet = lane>>4. C/D: col = lane&15, row = (lane>>4)*4+reg.
__global__ __launch_bounds__(256, 4) void gemm_k(const unsigned short* __restrict__ Ah,
                                                 const unsigned short* __restrict__ Al,
                                                 const unsigned short* __restrict__ Wph,
                                                 const unsigned short* __restrict__ Wpl,
                                                 const float* __restrict__ bias,
                                                 float* __restrict__ outZ,
                                                 int K,
                                                 const float* __restrict__ fvec,
                                                 const float* __restrict__ gproj,
                                                 float* __restrict__ part,
                                                 const float* __restrict__ W3,
                                                 const int* __restrict__ cnt,
                                                 float* __restrict__ zout) {
    __shared__ __align__(16) unsigned short sAh[64 * 128];   // [plane][row][8]  16 KB
    __shared__ __align__(16) unsigned short sAl[64 * 128];   // 16 KB
    __shared__ float zred[4 * 64];

    int t = threadIdx.x;
    int row0 = blockIdx.x * 64;
    int w = t >> 6;
    int l = t & 63;
    int lr = l & 15;
    int hg = l >> 4;

    f32x4 acc[4][2];
#pragma unroll
    for (int m = 0; m < 4; ++m)
#pragma unroll
        for (int n = 0; n < 2; ++n) acc[m][n] = (f32x4){0.f, 0.f, 0.f, 0.f};

    // stage ALL of A (K planes of [64 rows][8]) in one shot; per-thread nu uint4 pairs
    int nu = (K >> 3) << 6 >> 8;            // (K/8 planes * 64 rows) / 256 threads
    for (int i = 0; i < nu; ++i) {
        int u = t + i * 256;
        int p = u >> 6, r = u & 63;
        size_t src = ((size_t)p * NTOT + row0 + r) * 8;
        *(uint4*)&sAh[u * 8] = *(const uint4*)&Ah[src];
        *(uint4*)&sAl[u * 8] = *(const uint4*)&Al[src];
    }
    __syncthreads();                         // the ONLY pre-epilogue barrier

    int nk = K >> 5;
#pragma unroll 1
    for (int s = 0; s < nk; ++s) {
        int pb = s * 4 + hg;                 // this lane-group's k-plane
        bf16x8 ah[4], al[4], bh[2], bl[2];
#pragma unroll
        for (int m = 0; m < 4; ++m) {
            ah[m] = *(const bf16x8*)&sAh[(pb * 64 + m * 16 + lr) * 8];
            al[m] = *(const bf16x8*)&sAl[(pb * 64 + m * 16 + lr) * 8];
        }
#pragma unroll
        for (int n = 0; n < 2; ++n) {
            size_t wb = ((size_t)pb * 128 + w * 32 + n * 16 + lr) * 8;
            bh[n] = *(const bf16x8*)&Wph[wb];
            bl[n] = *(const bf16x8*)&Wpl[wb];
        }
#pragma unroll
        for (int m = 0; m < 4; ++m)
#pragma unroll
            for (int n = 0; n < 2; ++n) {
                acc[m][n] = __builtin_amdgcn_mfma_f32_16x16x32_bf16(ah[m], bh[n], acc[m][n], 0, 0, 0);
                acc[m][n] = __builtin_amdgcn_mfma_f32_16x16x32_bf16(al[m], bh[n], acc[m][n], 0, 0, 0);
                acc[m][n] = __builtin_amdgcn_mfma_f32_16x16x32_bf16(ah[m], bl[n], acc[m][n], 0, 0, 0);
            }
    }

    int g = row0 >> 10;
    int wc0 = w * 32;
    float bb[2], gp[2], w3c[2];
#pragma unroll
    for (int n = 0; n < 2; ++n) {
        int col = wc0 + n * 16 + lr;
        bb[n]  = bias[col];
        gp[n]  = fvec ? gproj[(size_t)g * 128 + col] : 0.f;
        w3c[n] = zout ? W3[col] : 0.f;
    }
    float fr[4][4];
    if (fvec) {
#pragma unroll
        for (int m = 0; m < 4; ++m)
#pragma unroll
            for (int r = 0; r < 4; ++r) fr[m][r] = fvec[row0 + m * 16 + hg * 4 + r];
    }
    float dvs[4][4];
    if (outZ) {
#pragma unroll
        for (int m = 0; m < 4; ++m)
#pragma unroll
            for (int r = 0; r < 4; ++r)
                dvs[m][r] = rsqrtf((float)cnt[row0 + m * 16 + hg * 4 + r] + 1.0f);
    }
    float zp[4][4];
#pragma unroll
    for (int m = 0; m < 4; ++m)
#pragma unroll
        for (int r = 0; r < 4; ++r) zp[m][r] = 0.f;
    float cmx[2] = {0.f, 0.f};

#pragma unroll
    for (int m = 0; m < 4; ++m)
#pragma unroll
        for (int n = 0; n < 2; ++n)
#pragma unroll
            for (int r = 0; r < 4; ++r) {
                float v = acc[m][n][r] + bb[n];
                if (fvec) v += fr[m][r] * gp[n];
                v = fmaxf(v, 0.f);
                if (part) cmx[n] = fmaxf(cmx[n], v);
                if (zout) zp[m][r] += v * w3c[n];
                if (outZ) {
                    int row = row0 + m * 16 + hg * 4 + r;
                    int cidx = w * 2 + n;
                    outZ[((size_t)cidx * NTOT + row) * 16 + lr] = v * dvs[m][r];
                }
            }

    if (part) {   // per-graph col-max: reduce across the wave's 64 rows, then atomicMax
#pragma unroll
        for (int n = 0; n < 2; ++n) {
            float v = cmx[n];
            v = fmaxf(v, __shfl_xor(v, 16));
            v = fmaxf(v, __shfl_xor(v, 32));
            if (hg == 0)
                atomicMax((int*)&part[(size_t)g * 128 + wc0 + n * 16 + lr],
                          __float_as_int(v));
        }
    }

    if (zout) {   // reduce row-dots across 16 col-lanes, then across 4 waves via LDS
#pragma unroll
        for (int m = 0; m < 4; ++m)
#pragma unroll
            for (int r = 0; r < 4; ++r) {
                float v = zp[m][r];
                v += __shfl_xor(v, 1);
                v += __shfl_xor(v, 2);
                v += __shfl_xor(v, 4);
                v += __shfl_xor(v, 8);
                zp[m][r] = v;
            }
        if (lr == 0) {
#pragma unroll
            for (int m = 0; m < 4; ++m)
#pragma unroll
                for (int r = 0; r < 4; ++r)
                    zred[w * 64 + m * 16 + hg * 4 + r] = zp[m][r];
        }
        __syncthreads();
        if (t < 64) {
            float sZ = zred[t] + zred[64 + t] + zred[128 + t] + zred[192 + t];
            zout[row0 + t] = sZ * rsqrtf((float)cnt[row0 + t] + 1.0f);
        }
    }
}

// ---------------- fused scalar-agg + top-K mask (one block per graph, 1024 thr) ------
__global__ __launch_bounds__(1024) void smask_k(const float* __restrict__ z,
                                                const unsigned short* __restrict__ col16,
                                                const int* __restrict__ cnt,
                                                const float* __restrict__ b3,
                                                float* __restrict__ out) {
    __shared__ float sz[1024];
    __shared__ float sl[1024];
    __shared__ float slo[1024];
    __shared__ float rv[16];
    __shared__ int   ri[16];
    __shared__ float sth;
    int g = blockIdx.x, t = threadIdx.x;
    int wv = t >> 6, ln = t & 63;
    int base = g << 10;
    sz[t] = z[base + t];
    __syncthreads();
    float bb = b3[0];
    {
        int gv = base + t;
        int n = cnt[gv];
        float dv = rsqrtf((float)n + 1.0f);
        float acc = sz[t];
        const unsigned short* ip = col16 + (size_t)gv * MAXDEG;   // node-major
        int j = 0;
        for (; j + 4 <= n; j += 4) {
            ushort4 s4 = *(const ushort4*)&ip[j];
            acc += (sz[s4.x] + sz[s4.y]) + (sz[s4.z] + sz[s4.w]);
        }
        for (; j < n; ++j) acc += sz[ip[j]];
        float lg = acc * dv + bb;
        sl[t] = lg; slo[t] = lg;
    }
    __syncthreads();
    for (int pass = 0; pass < KSEL; ++pass) {
        float bv = sl[t];
        int bi = t;
#pragma unroll
        for (int off = 32; off; off >>= 1) {   // wave argmax, deterministic tie-break
            float ov = __shfl_xor(bv, off);
            int   oi = __shfl_xor(bi, off);
            if (ov > bv || (ov == bv && oi < bi)) { bv = ov; bi = oi; }
        }
        if (ln == 0) { rv[wv] = bv; ri[wv] = bi; }
        __syncthreads();
        if (t == 0) {
            float mv = rv[0]; int mi = ri[0];
#pragma unroll
            for (int q = 1; q < 16; ++q)
                if (rv[q] > mv || (rv[q] == mv && ri[q] < mi)) { mv = rv[q]; mi = ri[q]; }
            sth = mv; sl[mi] = -INFINITY;
        }
        __syncthreads();
    }
    float th = sth;
    out[base + t] = (slo[t] >= th) ? 1.f : 0.f;
}

// =====================================================================================
extern "C" void kernel_launch(void* const* d_in, const int* in_sizes, int n_in,
                              void* d_out, int out_size, void* d_ws, size_t ws_size,
                              hipStream_t stream) {
    const float* x        = (const float*)d_in[0];
    const int*   edge_src = (const int*)d_in[1];
    const int*   edge_dst = (const int*)d_in[2];
    const float* W0 = (const float*)d_in[4];
    const float* b0 = (const float*)d_in[5];
    const float* W1 = (const float*)d_in[6];
    const float* b1 = (const float*)d_in[7];
    const float* Wf = (const float*)d_in[8];
    const float* bf = (const float*)d_in[9];
    const float* W2 = (const float*)d_in[10];
    const float* b2 = (const float*)d_in[11];
    const float* W3 = (const float*)d_in[12];
    const float* b3 = (const float*)d_in[13];
    float* out = (float*)d_out;

    char* w = (char*)d_ws;
    int*            cnt   = (int*)w;            w += (size_t)NTOT * 4;
    unsigned short* col16 = (unsigned short*)w; w += (size_t)NTOT * MAXDEG * 2;
    float*          fvec  = (float*)w;          w += (size_t)NTOT * 4;
    unsigned short* Ah    = (unsigned short*)w; w += (size_t)NTOT * 128 * 2;  // A hi
    unsigned short* Al    = (unsigned short*)w; w += (size_t)NTOT * 128 * 2;  // A lo
    float*          Q     = (float*)w;          w += (size_t)NTOT * 128 * 4;  // Z
    float*          part  = (float*)w;          w += (size_t)NB * 128 * 4;
    float*          gproj = (float*)w;          w += (size_t)NB * 128 * 4;
    float*          z     = (float*)w;          w += (size_t)NTOT * 4;
    unsigned short* Wph   = (unsigned short*)w; w += (size_t)320 * 128 * 2;   // packed W hi
    unsigned short* Wpl   = (unsigned short*)w; w += (size_t)320 * 128 * 2;   // packed W lo

    // csr (per-graph, LDS atomics; node-major col16) + pack + part-zero, one dispatch
    csrpack_k<<<NB + 41, 1024, 0, stream>>>(edge_src, edge_dst, cnt, col16,
                                            W0, W1, W2, Wph, Wpl, part);

    // conv0: A = agg(x) [K=64]; Z0 = relu(A@W0+b0)*dinv, fused maxpool -> part
    agg_k<<<NB * 4, 1024, 0, stream>>>(nullptr, x, col16, cnt, Ah, Al, 2, nullptr,
                                       nullptr, nullptr, nullptr, nullptr, nullptr);
    gemm_k<<<NTOT / 64, 256, 0, stream>>>(Ah, Al, Wph, Wpl, b0, Q, FEAT,
                                          nullptr, nullptr, part, nullptr, cnt, nullptr);

    // conv1 twice (same weights); first agg also carries the NB glob blocks
    agg_k<<<NB * 8 + NB, 1024, 0, stream>>>(Q, nullptr, col16, cnt, Ah, Al, 3, nullptr,
                                            Wf, bf, W2, gproj, part);
    gemm_k<<<NTOT / 64, 256, 0, stream>>>(Ah, Al, Wph + 64 * 128, Wpl + 64 * 128, b1, Q,
                                          HID, nullptr, nullptr, nullptr, nullptr, cnt,
                                          nullptr);
    agg_k<<<NB * 8, 1024, 0, stream>>>(Q, nullptr, col16, cnt, Ah, Al, 3, nullptr,
                                       nullptr, nullptr, nullptr, nullptr, nullptr);
    gemm_k<<<NTOT / 64, 256, 0, stream>>>(Ah, Al, Wph + 64 * 128, Wpl + 64 * 128, b1, Q,
                                          HID, nullptr, nullptr, nullptr, nullptr, cnt,
                                          nullptr);

    // conv2: A = agg(Z2) (+fvec); z = dinv*(relu(A@W2a + f*gproj + b2)@W3)
    agg_k<<<NB * 8, 1024, 0, stream>>>(Q, nullptr, col16, cnt, Ah, Al, 3, fvec,
                                       nullptr, nullptr, nullptr, nullptr, nullptr);
    gemm_k<<<NTOT / 64, 256, 0, stream>>>(Ah, Al, Wph + 192 * 128, Wpl + 192 * 128, b2,
                                          nullptr, HID, fvec, gproj, nullptr, W3, cnt, z);

    // logits = agg_scalar(z) + b3, then per-graph top-10 mask (fused)
    smask_k<<<NB, 1024, 0, stream>>>(z, col16, cnt, b3, out);
}

// Round 10
// 326.181 us; speedup vs baseline: 1.1592x; 1.1592x over previous
//
#include <hip/hip_runtime.h>
#include <math.h>

#define NB    64        // graphs
#define NPER  1024      // nodes per graph
#define NTOT  65536     // total nodes
#define ETOT  1048576   // edges
#define FEAT  64
#define HID   128
#define KSEL  10
#define MAXDEG 64       // CSR slot capacity per node (max in-degree ~40)

// Pipeline (agg commuted before the weight multiply, dinv folded into gemm output):
//   A = agg(Z)             agg_k  : LDS-staged gather, ONE NODE PER THREAD (indices
//                                   loaded once, coalesced u16; 4..8 b128 reads in
//                                   flight; swizzled LDS quads) -> k-octet bf16 hi/lo
//   Z' = relu(A@W+b)*dinv  gemm_k : 64x128 MFMA tile, bf16x3 (hi*hi+hi*lo+lo*hi)
// csrpack_k: per-graph CSR in LDS atomics, SLOT-MAJOR col16[slot*NTOT+node] (R7-best:
//   wave reads 64 consecutive u16 = one 128B line) + pack/part-zero tails.
// LDS quad swizzle SQ(v,q)=v*4+(q^(v&3)): with one-node-per-thread the gather reads
//   quad q wave-uniform; unswizzled starts land on 2 bank-quads (32-way). Swizzle
//   spreads starts uniformly over all 8. Writer/self/gather share the map.
// R9 lesson: NO launch_bounds min-waves on agg (forced spills -> 2x HBM traffic).
// R6 lesson: do NOT fuse the gather into the GEMM (17x L3 traffic at 1.9 TB/s).

typedef __attribute__((ext_vector_type(8))) short bf16x8;
typedef __attribute__((ext_vector_type(4))) float f32x4;

#define SQ(v, q) (((v) << 2) + ((q) ^ ((v) & 3)))

static __device__ __forceinline__ unsigned short f2bf(float x) {   // RNE fp32->bf16
    unsigned u = __float_as_uint(x);
    return (unsigned short)((u + 0x7FFFu + ((u >> 16) & 1u)) >> 16);
}
static __device__ __forceinline__ float bf2f(unsigned short s) {
    return __uint_as_float(((unsigned)s) << 16);
}

// ------- CSR build (per-graph LDS atomics, slot-major) + pack + part-zero tail -----
__global__ __launch_bounds__(1024) void csrpack_k(const int* __restrict__ src,
                                                  const int* __restrict__ dst,
                                                  int* __restrict__ cnt,
                                                  unsigned short* __restrict__ col16,
                                                  const float* __restrict__ W0,
                                                  const float* __restrict__ W1,
                                                  const float* __restrict__ W2,
                                                  unsigned short* __restrict__ Wph,
                                                  unsigned short* __restrict__ Wpl,
                                                  float* __restrict__ part) {
    int t = threadIdx.x;
    int b = blockIdx.x;
    if (b >= NB) {
        int pb = b - NB;
        if (pb == 40) {   // zero atomicMax target (relu>=0 so 0.0f bits are the floor)
            for (int i = t; i < NB * 128; i += 1024) part[i] = 0.f;
            return;
        }
        int idx = pb * 1024 + t;          // 0..40959 covers 320*128
        if (idx >= 320 * 128) return;
        int k = idx >> 7;
        int c = idx & 127;
        float v;
        size_t mb;
        int kk;
        if (k < 64)       { kk = k;       v = W0[kk * 128 + c]; mb = 0; }
        else if (k < 192) { kk = k - 64;  v = W1[kk * 128 + c]; mb = (size_t)64 * 128; }
        else              { kk = k - 192; v = W2[kk * 128 + c]; mb = (size_t)192 * 128; }
        unsigned short h  = f2bf(v);
        unsigned short lo = f2bf(v - bf2f(h));
        size_t d = mb + ((size_t)(kk >> 3) * 128 + c) * 8 + (kk & 7);
        Wph[d] = h;
        Wpl[d] = lo;
        return;
    }
    // per-graph CSR, slot-major output
    __shared__ int lcnt[NPER];
    int g = b;
    int gbase = g << 10;
    int ebase = g * (NPER * 16);          // DEG=16, graph-contiguous edge rows
    lcnt[t] = 0;
    __syncthreads();
    const int4* ds4 = (const int4*)(dst + ebase);
    const int4* ss4 = (const int4*)(src + ebase);
#pragma unroll 1
    for (int i = 0; i < 4; ++i) {
        int e4 = i * 1024 + t;            // 4096 int4 groups cover 16384 edges
        int4 dv = ds4[e4];
        int4 sv = ss4[e4];
        int d0 = dv.x & (NPER - 1), s0 = sv.x & (NPER - 1);
        int d1 = dv.y & (NPER - 1), s1 = sv.y & (NPER - 1);
        int d2 = dv.z & (NPER - 1), s2 = sv.z & (NPER - 1);
        int d3 = dv.w & (NPER - 1), s3 = sv.w & (NPER - 1);
        int p0 = atomicAdd(&lcnt[d0], 1);
        col16[(size_t)p0 * NTOT + gbase + d0] = (unsigned short)s0;
        int p1 = atomicAdd(&lcnt[d1], 1);
        col16[(size_t)p1 * NTOT + gbase + d1] = (unsigned short)s1;
        int p2 = atomicAdd(&lcnt[d2], 1);
        col16[(size_t)p2 * NTOT + gbase + d2] = (unsigned short)s2;
        int p3 = atomicAdd(&lcnt[d3], 1);
        col16[(size_t)p3 * NTOT + gbase + d3] = (unsigned short)s3;
    }
    __syncthreads();
    cnt[gbase + t] = lcnt[t];
}

// ---------------- LDS-staged aggregation, one node per thread ----------------------
// block=(graph g, chunk c of 16 feats). out_v = dv * sum(staged over {v} u N(v)).
// If Wf != nullptr, the LAST NB blocks instead compute glob/gproj (fused glob_k).
__global__ __launch_bounds__(1024) void agg_k(const float* __restrict__ Z,
                                              const float* __restrict__ x,
                                              const unsigned short* __restrict__ col16,
                                              const int* __restrict__ cnt,
                                              unsigned short* __restrict__ Ah,
                                              unsigned short* __restrict__ Al,
                                              int cshift,
                                              float* __restrict__ fvec,
                                              const float* __restrict__ Wf,
                                              const float* __restrict__ bfv,
                                              const float* __restrict__ W2g,
                                              float* __restrict__ gproj,
                                              const float* __restrict__ part) {
    __shared__ float4 sy4[4096];   // 64 KB
    int t = threadIdx.x;

    if (Wf && (int)blockIdx.x >= (int)gridDim.x - NB) {   // fused glob block
        float* sm = (float*)sy4;
        float* mp = sm;            // 128
        float* ps = sm + 128;      // 1024
        float* gl = sm + 128 + 1024;
        int gg = blockIdx.x - (gridDim.x - NB);
        int o = t & 127, s8 = t >> 7;       // 8 segments of 16 k each
        if (t < 128) mp[t] = part[(size_t)gg * 128 + t];
        __syncthreads();
        float p = 0.f;
#pragma unroll
        for (int q = 0; q < 16; ++q) { int k = s8 * 16 + q; p += mp[k] * Wf[(size_t)k * 128 + o]; }
        ps[t] = p;
        __syncthreads();
        if (t < 128) {
            float a = bfv[t];
#pragma unroll
            for (int q = 0; q < 8; ++q) a += ps[q * 128 + t];
            gl[t] = a;
        }
        __syncthreads();
        p = 0.f;
#pragma unroll
        for (int q = 0; q < 16; ++q) { int k = s8 * 16 + q; p += gl[k] * W2g[(size_t)(128 + k) * 128 + o]; }
        ps[t] = p;
        __syncthreads();
        if (t < 128) {
            float a = 0.f;
#pragma unroll
            for (int q = 0; q < 8; ++q) a += ps[q * 128 + t];
            gproj[(size_t)gg * 128 + t] = a;
        }
        return;
    }

    int g = blockIdx.x >> cshift;
    int c = blockIdx.x & ((1 << cshift) - 1);
    int gbase = g << 10;

    if (x) {
#pragma unroll
        for (int j = 0; j < 4; ++j) {
            int fl = j * 1024 + t;
            int v = fl >> 2, q = fl & 3;
            float dvv = rsqrtf((float)cnt[gbase + v] + 1.0f);
            float4 z = *(const float4*)&x[(size_t)(gbase + v) * FEAT + c * 16 + q * 4];
            z.x *= dvv; z.y *= dvv; z.z *= dvv; z.w *= dvv;
            sy4[SQ(v, q)] = z;
        }
    } else {
        const float4* Zg4 = (const float4*)(Z + ((size_t)c * NTOT + gbase) * 16);
#pragma unroll
        for (int j = 0; j < 4; ++j) {
            int fl = j * 1024 + t;
            int v = fl >> 2, q = fl & 3;
            sy4[SQ(v, q)] = Zg4[fl];
        }
    }
    __syncthreads();

    // one node per thread: full 16-feat chunk, indices loaded once (coalesced u16)
    int v = t;
    int gv = gbase + v;
    int n = cnt[gv];
    float dv = rsqrtf((float)n + 1.0f);
    const unsigned short* ip = col16 + gv;   // slot-major: ip[slot*NTOT]
    float4 a0 = sy4[SQ(v, 0)];               // self terms
    float4 a1 = sy4[SQ(v, 1)];
    float4 a2 = sy4[SQ(v, 2)];
    float4 a3 = sy4[SQ(v, 3)];
    int i = 0;
    for (; i + 2 <= n; i += 2) {             // 2 idx loads + 8 b128 reads in flight
        int pa = ip[(size_t)i * NTOT];
        int pb = ip[(size_t)(i + 1) * NTOT];
        float4 ya0 = sy4[SQ(pa, 0)];
        float4 ya1 = sy4[SQ(pa, 1)];
        float4 ya2 = sy4[SQ(pa, 2)];
        float4 ya3 = sy4[SQ(pa, 3)];
        float4 yb0 = sy4[SQ(pb, 0)];
        float4 yb1 = sy4[SQ(pb, 1)];
        float4 yb2 = sy4[SQ(pb, 2)];
        float4 yb3 = sy4[SQ(pb, 3)];
        a0.x += ya0.x + yb0.x; a0.y += ya0.y + yb0.y; a0.z += ya0.z + yb0.z; a0.w += ya0.w + yb0.w;
        a1.x += ya1.x + yb1.x; a1.y += ya1.y + yb1.y; a1.z += ya1.z + yb1.z; a1.w += ya1.w + yb1.w;
        a2.x += ya2.x + yb2.x; a2.y += ya2.y + yb2.y; a2.z += ya2.z + yb2.z; a2.w += ya2.w + yb2.w;
        a3.x += ya3.x + yb3.x; a3.y += ya3.y + yb3.y; a3.z += ya3.z + yb3.z; a3.w += ya3.w + yb3.w;
    }
    if (i < n) {
        int pa = ip[(size_t)i * NTOT];
        float4 ya0 = sy4[SQ(pa, 0)];
        float4 ya1 = sy4[SQ(pa, 1)];
        float4 ya2 = sy4[SQ(pa, 2)];
        float4 ya3 = sy4[SQ(pa, 3)];
        a0.x += ya0.x; a0.y += ya0.y; a0.z += ya0.z; a0.w += ya0.w;
        a1.x += ya1.x; a1.y += ya1.y; a1.z += ya1.z; a1.w += ya1.w;
        a2.x += ya2.x; a2.y += ya2.y; a2.z += ya2.z; a2.w += ya2.w;
        a3.x += ya3.x; a3.y += ya3.y; a3.z += ya3.z; a3.w += ya3.w;
    }
    a0.x *= dv; a0.y *= dv; a0.z *= dv; a0.w *= dv;
    a1.x *= dv; a1.y *= dv; a1.z *= dv; a1.w *= dv;
    a2.x *= dv; a2.y *= dv; a2.z *= dv; a2.w *= dv;
    a3.x *= dv; a3.y *= dv; a3.z *= dv; a3.w *= dv;

    // quad q = feats c*16+q*4 .. +3 -> plane 2c+(q>>1), half (q&1)*4.
    // thread writes 16B contiguous per plane; consecutive gv -> coalesced 1KB/wave.
    {
        ushort4 h, lo;
        size_t ba = ((size_t)(2 * c) * NTOT + gv) * 8;
        h.x = f2bf(a0.x); lo.x = f2bf(a0.x - bf2f(h.x));
        h.y = f2bf(a0.y); lo.y = f2bf(a0.y - bf2f(h.y));
        h.z = f2bf(a0.z); lo.z = f2bf(a0.z - bf2f(h.z));
        h.w = f2bf(a0.w); lo.w = f2bf(a0.w - bf2f(h.w));
        *(ushort4*)&Ah[ba] = h;
        *(ushort4*)&Al[ba] = lo;
        h.x = f2bf(a1.x); lo.x = f2bf(a1.x - bf2f(h.x));
        h.y = f2bf(a1.y); lo.y = f2bf(a1.y - bf2f(h.y));
        h.z = f2bf(a1.z); lo.z = f2bf(a1.z - bf2f(h.z));
        h.w = f2bf(a1.w); lo.w = f2bf(a1.w - bf2f(h.w));
        *(ushort4*)&Ah[ba + 4] = h;
        *(ushort4*)&Al[ba + 4] = lo;
        size_t bb = ((size_t)(2 * c + 1) * NTOT + gv) * 8;
        h.x = f2bf(a2.x); lo.x = f2bf(a2.x - bf2f(h.x));
        h.y = f2bf(a2.y); lo.y = f2bf(a2.y - bf2f(h.y));
        h.z = f2bf(a2.z); lo.z = f2bf(a2.z - bf2f(h.z));
        h.w = f2bf(a2.w); lo.w = f2bf(a2.w - bf2f(h.w));
        *(ushort4*)&Ah[bb] = h;
        *(ushort4*)&Al[bb] = lo;
        h.x = f2bf(a3.x); lo.x = f2bf(a3.x - bf2f(h.x));
        h.y = f2bf(a3.y); lo.y = f2bf(a3.y - bf2f(h.y));
        h.z = f2bf(a3.z); lo.z = f2bf(a3.z - bf2f(h.z));
        h.w = f2bf(a3.w); lo.w = f2bf(a3.w - bf2f(h.w));
        *(ushort4*)&Ah[bb + 4] = h;
        *(ushort4*)&Al[bb + 4] = lo;
    }

    if (fvec && c == 0) {   // f_v = dinv_v*(dinv_v + sum dinv_s)
        __syncthreads();
        float* sdv = (float*)sy4;
        float dvv = rsqrtf((float)cnt[gbase + t] + 1.0f);
        sdv[t] = dvv;
        __syncthreads();
        int nn = cnt[gbase + t];
        float acc = dvv;
        const unsigned short* ipf = col16 + gbase + t;
        for (int j = 0; j < nn; ++j) acc += sdv[ipf[(size_t)j * NTOT]];
        fvec[gbase + t] = dvv * acc;
    }
}

// ---------------- bf16x3 MFMA GEMM: 64 rows x 128 cols per block, fused epilogue ----
// Single-shot A staging (whole K, 32 KB hi+lo, ONE barrier), B frags straight from L2.
// A frag: row = lane&15, k-octet = lane>>4. C/D: col = lane&15, row = (lane>>4)*4+reg.
__global__ __launch_bounds__(256, 4) void gemm_k(const unsigned short* __restrict__ Ah,
                                                 const unsigned short* __restrict__ Al,
                                                 const unsigned short* __restrict__ Wph,
                                                 const unsigned short* __restrict__ Wpl,
                                                 const float* __restrict__ bias,
                                                 float* __restrict__ outZ,
                                                 int K,
                                                 const float* __restrict__ fvec,
                                                 const float* __restrict__ gproj,
                                                 float* __restrict__ part,
                                                 const float* __restrict__ W3,
                                                 const int* __restrict__ cnt,
                                                 float* __restrict__ zout) {
    __shared__ __align__(16) unsigned short sAh[64 * 128];   // [plane][row][8]  16 KB
    __shared__ __align__(16) unsigned short sAl[64 * 128];   // 16 KB
    __shared__ float zred[4 * 64];

    int t = threadIdx.x;
    int row0 = blockIdx.x * 64;
    int w = t >> 6;
    int l = t & 63;
    int lr = l & 15;
    int hg = l >> 4;

    f32x4 acc[4][2];
#pragma unroll
    for (int m = 0; m < 4; ++m)
#pragma unroll
        for (int n = 0; n < 2; ++n) acc[m][n] = (f32x4){0.f, 0.f, 0.f, 0.f};

    // stage ALL of A (K planes of [64 rows][8]) in one shot; per-thread nu uint4 pairs
    int nu = (K >> 3) << 6 >> 8;            // (K/8 planes * 64 rows) / 256 threads
    for (int i = 0; i < nu; ++i) {
        int u = t + i * 256;
        int p = u >> 6, r = u & 63;
        size_t src = ((size_t)p * NTOT + row0 + r) * 8;
        *(uint4*)&sAh[u * 8] = *(const uint4*)&Ah[src];
        *(uint4*)&sAl[u * 8] = *(const uint4*)&Al[src];
    }
    __syncthreads();                         // the ONLY pre-epilogue barrier

    int nk = K >> 5;
#pragma unroll 1
    for (int s = 0; s < nk; ++s) {
        int pb = s * 4 + hg;                 // this lane-group's k-plane
        bf16x8 ah[4], al[4], bh[2], bl[2];
#pragma unroll
        for (int m = 0; m < 4; ++m) {
            ah[m] = *(const bf16x8*)&sAh[(pb * 64 + m * 16 + lr) * 8];
            al[m] = *(const bf16x8*)&sAl[(pb * 64 + m * 16 + lr) * 8];
        }
#pragma unroll
        for (int n = 0; n < 2; ++n) {
            size_t wb = ((size_t)pb * 128 + w * 32 + n * 16 + lr) * 8;
            bh[n] = *(const bf16x8*)&Wph[wb];
            bl[n] = *(const bf16x8*)&Wpl[wb];
        }
#pragma unroll
        for (int m = 0; m < 4; ++m)
#pragma unroll
            for (int n = 0; n < 2; ++n) {
                acc[m][n] = __builtin_amdgcn_mfma_f32_16x16x32_bf16(ah[m], bh[n], acc[m][n], 0, 0, 0);
                acc[m][n] = __builtin_amdgcn_mfma_f32_16x16x32_bf16(al[m], bh[n], acc[m][n], 0, 0, 0);
                acc[m][n] = __builtin_amdgcn_mfma_f32_16x16x32_bf16(ah[m], bl[n], acc[m][n], 0, 0, 0);
            }
    }

    int g = row0 >> 10;
    int wc0 = w * 32;
    float bb[2], gp[2], w3c[2];
#pragma unroll
    for (int n = 0; n < 2; ++n) {
        int col = wc0 + n * 16 + lr;
        bb[n]  = bias[col];
        gp[n]  = fvec ? gproj[(size_t)g * 128 + col] : 0.f;
        w3c[n] = zout ? W3[col] : 0.f;
    }
    float fr[4][4];
    if (fvec) {
#pragma unroll
        for (int m = 0; m < 4; ++m)
#pragma unroll
            for (int r = 0; r < 4; ++r) fr[m][r] = fvec[row0 + m * 16 + hg * 4 + r];
    }
    float dvs[4][4];
    if (outZ) {
#pragma unroll
        for (int m = 0; m < 4; ++m)
#pragma unroll
            for (int r = 0; r < 4; ++r)
                dvs[m][r] = rsqrtf((float)cnt[row0 + m * 16 + hg * 4 + r] + 1.0f);
    }
    float zp[4][4];
#pragma unroll
    for (int m = 0; m < 4; ++m)
#pragma unroll
        for (int r = 0; r < 4; ++r) zp[m][r] = 0.f;
    float cmx[2] = {0.f, 0.f};

#pragma unroll
    for (int m = 0; m < 4; ++m)
#pragma unroll
        for (int n = 0; n < 2; ++n)
#pragma unroll
            for (int r = 0; r < 4; ++r) {
                float v = acc[m][n][r] + bb[n];
                if (fvec) v += fr[m][r] * gp[n];
                v = fmaxf(v, 0.f);
                if (part) cmx[n] = fmaxf(cmx[n], v);
                if (zout) zp[m][r] += v * w3c[n];
                if (outZ) {
                    int row = row0 + m * 16 + hg * 4 + r;
                    int cidx = w * 2 + n;
                    outZ[((size_t)cidx * NTOT + row) * 16 + lr] = v * dvs[m][r];
                }
            }

    if (part) {   // per-graph col-max: reduce across the wave's 64 rows, then atomicMax
#pragma unroll
        for (int n = 0; n < 2; ++n) {
            float v = cmx[n];
            v = fmaxf(v, __shfl_xor(v, 16));
            v = fmaxf(v, __shfl_xor(v, 32));
            if (hg == 0)
                atomicMax((int*)&part[(size_t)g * 128 + wc0 + n * 16 + lr],
                          __float_as_int(v));
        }
    }

    if (zout) {   // reduce row-dots across 16 col-lanes, then across 4 waves via LDS
#pragma unroll
        for (int m = 0; m < 4; ++m)
#pragma unroll
            for (int r = 0; r < 4; ++r) {
                float v = zp[m][r];
                v += __shfl_xor(v, 1);
                v += __shfl_xor(v, 2);
                v += __shfl_xor(v, 4);
                v += __shfl_xor(v, 8);
                zp[m][r] = v;
            }
        if (lr == 0) {
#pragma unroll
            for (int m = 0; m < 4; ++m)
#pragma unroll
                for (int r = 0; r < 4; ++r)
                    zred[w * 64 + m * 16 + hg * 4 + r] = zp[m][r];
        }
        __syncthreads();
        if (t < 64) {
            float sZ = zred[t] + zred[64 + t] + zred[128 + t] + zred[192 + t];
            zout[row0 + t] = sZ * rsqrtf((float)cnt[row0 + t] + 1.0f);
        }
    }
}

// ---------------- fused scalar-agg + top-K mask (one block per graph, 1024 thr) ------
__global__ __launch_bounds__(1024) void smask_k(const float* __restrict__ z,
                                                const unsigned short* __restrict__ col16,
                                                const int* __restrict__ cnt,
                                                const float* __restrict__ b3,
                                                float* __restrict__ out) {
    __shared__ float sz[1024];
    __shared__ float sl[1024];
    __shared__ float slo[1024];
    __shared__ float rv[16];
    __shared__ int   ri[16];
    __shared__ float sth;
    int g = blockIdx.x, t = threadIdx.x;
    int wv = t >> 6, ln = t & 63;
    int base = g << 10;
    sz[t] = z[base + t];
    __syncthreads();
    float bb = b3[0];
    {
        int gv = base + t;
        int n = cnt[gv];
        float dv = rsqrtf((float)n + 1.0f);
        float acc = sz[t];
        const unsigned short* ip = col16 + gv;   // slot-major, coalesced
        int j = 0;
        for (; j + 2 <= n; j += 2)
            acc += sz[ip[(size_t)j * NTOT]] + sz[ip[(size_t)(j + 1) * NTOT]];
        for (; j < n; ++j) acc += sz[ip[(size_t)j * NTOT]];
        float lg = acc * dv + bb;
        sl[t] = lg; slo[t] = lg;
    }
    __syncthreads();
    for (int pass = 0; pass < KSEL; ++pass) {
        float bv = sl[t];
        int bi = t;
#pragma unroll
        for (int off = 32; off; off >>= 1) {   // wave argmax, deterministic tie-break
            float ov = __shfl_xor(bv, off);
            int   oi = __shfl_xor(bi, off);
            if (ov > bv || (ov == bv && oi < bi)) { bv = ov; bi = oi; }
        }
        if (ln == 0) { rv[wv] = bv; ri[wv] = bi; }
        __syncthreads();
        if (t == 0) {
            float mv = rv[0]; int mi = ri[0];
#pragma unroll
            for (int q = 1; q < 16; ++q)
                if (rv[q] > mv || (rv[q] == mv && ri[q] < mi)) { mv = rv[q]; mi = ri[q]; }
            sth = mv; sl[mi] = -INFINITY;
        }
        __syncthreads();
    }
    float th = sth;
    out[base + t] = (slo[t] >= th) ? 1.f : 0.f;
}

// =====================================================================================
extern "C" void kernel_launch(void* const* d_in, const int* in_sizes, int n_in,
                              void* d_out, int out_size, void* d_ws, size_t ws_size,
                              hipStream_t stream) {
    const float* x        = (const float*)d_in[0];
    const int*   edge_src = (const int*)d_in[1];
    const int*   edge_dst = (const int*)d_in[2];
    const float* W0 = (const float*)d_in[4];
    const float* b0 = (const float*)d_in[5];
    const float* W1 = (const float*)d_in[6];
    const float* b1 = (const float*)d_in[7];
    const float* Wf = (const float*)d_in[8];
    const float* bf = (const float*)d_in[9];
    const float* W2 = (const float*)d_in[10];
    const float* b2 = (const float*)d_in[11];
    const float* W3 = (const float*)d_in[12];
    const float* b3 = (const float*)d_in[13];
    float* out = (float*)d_out;

    char* w = (char*)d_ws;
    int*            cnt   = (int*)w;            w += (size_t)NTOT * 4;
    unsigned short* col16 = (unsigned short*)w; w += (size_t)NTOT * MAXDEG * 2;
    float*          fvec  = (float*)w;          w += (size_t)NTOT * 4;
    unsigned short* Ah    = (unsigned short*)w; w += (size_t)NTOT * 128 * 2;  // A hi
    unsigned short* Al    = (unsigned short*)w; w += (size_t)NTOT * 128 * 2;  // A lo
    float*          Q     = (float*)w;          w += (size_t)NTOT * 128 * 4;  // Z
    float*          part  = (float*)w;          w += (size_t)NB * 128 * 4;
    float*          gproj = (float*)w;          w += (size_t)NB * 128 * 4;
    float*          z     = (float*)w;          w += (size_t)NTOT * 4;
    unsigned short* Wph   = (unsigned short*)w; w += (size_t)320 * 128 * 2;   // packed W hi
    unsigned short* Wpl   = (unsigned short*)w; w += (size_t)320 * 128 * 2;   // packed W lo

    // csr (per-graph, LDS atomics; slot-major col16) + pack + part-zero, one dispatch
    csrpack_k<<<NB + 41, 1024, 0, stream>>>(edge_src, edge_dst, cnt, col16,
                                            W0, W1, W2, Wph, Wpl, part);

    // conv0: A = agg(x) [K=64]; Z0 = relu(A@W0+b0)*dinv, fused maxpool -> part
    agg_k<<<NB * 4, 1024, 0, stream>>>(nullptr, x, col16, cnt, Ah, Al, 2, nullptr,
                                       nullptr, nullptr, nullptr, nullptr, nullptr);
    gemm_k<<<NTOT / 64, 256, 0, stream>>>(Ah, Al, Wph, Wpl, b0, Q, FEAT,
                                          nullptr, nullptr, part, nullptr, cnt, nullptr);

    // conv1 twice (same weights); first agg also carries the NB glob blocks
    agg_k<<<NB * 8 + NB, 1024, 0, stream>>>(Q, nullptr, col16, cnt, Ah, Al, 3, nullptr,
                                            Wf, bf, W2, gproj, part);
    gemm_k<<<NTOT / 64, 256, 0, stream>>>(Ah, Al, Wph + 64 * 128, Wpl + 64 * 128, b1, Q,
                                          HID, nullptr, nullptr, nullptr, nullptr, cnt,
                                          nullptr);
    agg_k<<<NB * 8, 1024, 0, stream>>>(Q, nullptr, col16, cnt, Ah, Al, 3, nullptr,
                                       nullptr, nullptr, nullptr, nullptr, nullptr);
    gemm_k<<<NTOT / 64, 256, 0, stream>>>(Ah, Al, Wph + 64 * 128, Wpl + 64 * 128, b1, Q,
                                          HID, nullptr, nullptr, nullptr, nullptr, cnt,
                                          nullptr);

    // conv2: A = agg(Z2) (+fvec); z = dinv*(relu(A@W2a + f*gproj + b2)@W3)
    agg_k<<<NB * 8, 1024, 0, stream>>>(Q, nullptr, col16, cnt, Ah, Al, 3, fvec,
                                       nullptr, nullptr, nullptr, nullptr, nullptr);
    gemm_k<<<NTOT / 64, 256, 0, stream>>>(Ah, Al, Wph + 192 * 128, Wpl + 192 * 128, b2,
                                          nullptr, HID, fvec, gproj, nullptr, W3, cnt, z);

    // logits = agg_scalar(z) + b3, then per-graph top-10 mask (fused)
    smask_k<<<NB, 1024, 0, stream>>>(z, col16, cnt, b3, out);
}

// Round 11
// 283.482 us; speedup vs baseline: 1.3338x; 1.1506x over previous
//
#include <hip/hip_runtime.h>
#include <math.h>

#define NB    64        // graphs
#define NPER  1024      // nodes per graph
#define NTOT  65536     // total nodes
#define ETOT  1048576   // edges
#define FEAT  64
#define HID   128
#define KSEL  10
#define MAXDEG 64       // CSR slot capacity per node (max in-degree ~40)

// Pipeline (agg commuted before the weight multiply, dinv folded into gemm output):
//   A = agg(Z)             agg_k  : LDS-staged gather (dedupes neighbor reads); output
//                                   k-octet-major bf16 hi/lo Ah/Al[(k>>3)][v][k&7]
//   Z' = relu(A@W+b)*dinv  gemm_k : 64x128 MFMA tile, bf16x3 (hi*hi+hi*lo+lo*hi)
// csrpack_k: per-graph CSR in LDS atomics, SLOT-MAJOR col16[slot*NTOT+node] (wave
//   reads 64 consecutive u16 = one 128B line) + pack/part-zero tails (one dispatch).
// agg gather: R7 mapping (4 threads/node, 16 nodes/wave -> consecutive quads, bank-
//   uniform) + INDEX SOFTWARE PREFETCH: next index quad loaded before current group's
//   LDS reads, hiding the ~200-400cy L2 index latency in the dependent chain.
// Lessons: R6 do NOT fuse gather into GEMM (17x L3 traffic @1.9TB/s). R9 no min-waves
//   launch_bounds on agg (spills -> 2x HBM). R10 per-lane random LDS quads -> 7x bank
//   conflicts; keep the R7 consecutive-quad mapping.

typedef __attribute__((ext_vector_type(8))) short bf16x8;
typedef __attribute__((ext_vector_type(4))) float f32x4;

static __device__ __forceinline__ unsigned short f2bf(float x) {   // RNE fp32->bf16
    unsigned u = __float_as_uint(x);
    return (unsigned short)((u + 0x7FFFu + ((u >> 16) & 1u)) >> 16);
}
static __device__ __forceinline__ float bf2f(unsigned short s) {
    return __uint_as_float(((unsigned)s) << 16);
}

// ------- CSR build (per-graph LDS atomics, slot-major) + pack + part-zero tail -----
__global__ __launch_bounds__(1024) void csrpack_k(const int* __restrict__ src,
                                                  const int* __restrict__ dst,
                                                  int* __restrict__ cnt,
                                                  unsigned short* __restrict__ col16,
                                                  const float* __restrict__ W0,
                                                  const float* __restrict__ W1,
                                                  const float* __restrict__ W2,
                                                  unsigned short* __restrict__ Wph,
                                                  unsigned short* __restrict__ Wpl,
                                                  float* __restrict__ part) {
    int t = threadIdx.x;
    int b = blockIdx.x;
    if (b >= NB) {
        int pb = b - NB;
        if (pb == 40) {   // zero atomicMax target (relu>=0 so 0.0f bits are the floor)
            for (int i = t; i < NB * 128; i += 1024) part[i] = 0.f;
            return;
        }
        int idx = pb * 1024 + t;          // 0..40959 covers 320*128
        if (idx >= 320 * 128) return;
        int k = idx >> 7;
        int c = idx & 127;
        float v;
        size_t mb;
        int kk;
        if (k < 64)       { kk = k;       v = W0[kk * 128 + c]; mb = 0; }
        else if (k < 192) { kk = k - 64;  v = W1[kk * 128 + c]; mb = (size_t)64 * 128; }
        else              { kk = k - 192; v = W2[kk * 128 + c]; mb = (size_t)192 * 128; }
        unsigned short h  = f2bf(v);
        unsigned short lo = f2bf(v - bf2f(h));
        size_t d = mb + ((size_t)(kk >> 3) * 128 + c) * 8 + (kk & 7);
        Wph[d] = h;
        Wpl[d] = lo;
        return;
    }
    // per-graph CSR, slot-major output
    __shared__ int lcnt[NPER];
    int g = b;
    int gbase = g << 10;
    int ebase = g * (NPER * 16);          // DEG=16, graph-contiguous edge rows
    lcnt[t] = 0;
    __syncthreads();
    const int4* ds4 = (const int4*)(dst + ebase);
    const int4* ss4 = (const int4*)(src + ebase);
#pragma unroll 1
    for (int i = 0; i < 4; ++i) {
        int e4 = i * 1024 + t;            // 4096 int4 groups cover 16384 edges
        int4 dv = ds4[e4];
        int4 sv = ss4[e4];
        int d0 = dv.x & (NPER - 1), s0 = sv.x & (NPER - 1);
        int d1 = dv.y & (NPER - 1), s1 = sv.y & (NPER - 1);
        int d2 = dv.z & (NPER - 1), s2 = sv.z & (NPER - 1);
        int d3 = dv.w & (NPER - 1), s3 = sv.w & (NPER - 1);
        int p0 = atomicAdd(&lcnt[d0], 1);
        col16[(size_t)p0 * NTOT + gbase + d0] = (unsigned short)s0;
        int p1 = atomicAdd(&lcnt[d1], 1);
        col16[(size_t)p1 * NTOT + gbase + d1] = (unsigned short)s1;
        int p2 = atomicAdd(&lcnt[d2], 1);
        col16[(size_t)p2 * NTOT + gbase + d2] = (unsigned short)s2;
        int p3 = atomicAdd(&lcnt[d3], 1);
        col16[(size_t)p3 * NTOT + gbase + d3] = (unsigned short)s3;
    }
    __syncthreads();
    cnt[gbase + t] = lcnt[t];
}

// ---------------- LDS-staged aggregation -> k-octet-major bf16 hi/lo output --------
// block=(graph g, chunk c). Z input is pre-scaled by dinv (gemm did it); x input
// (conv0) scaled here. out_v = dv * sum(staged over {v} u N(v)), split hi/lo.
// If Wf != nullptr, the LAST NB blocks instead compute glob/gproj (fused glob_k).
__global__ __launch_bounds__(1024) void agg_k(const float* __restrict__ Z,
                                              const float* __restrict__ x,
                                              const unsigned short* __restrict__ col16,
                                              const int* __restrict__ cnt,
                                              unsigned short* __restrict__ Ah,
                                              unsigned short* __restrict__ Al,
                                              int cshift,
                                              float* __restrict__ fvec,
                                              const float* __restrict__ Wf,
                                              const float* __restrict__ bfv,
                                              const float* __restrict__ W2g,
                                              float* __restrict__ gproj,
                                              const float* __restrict__ part) {
    __shared__ float4 sy4[4096];   // 64 KB
    int t = threadIdx.x;

    if (Wf && (int)blockIdx.x >= (int)gridDim.x - NB) {   // fused glob block
        float* sm = (float*)sy4;
        float* mp = sm;            // 128
        float* ps = sm + 128;      // 1024
        float* gl = sm + 128 + 1024;
        int gg = blockIdx.x - (gridDim.x - NB);
        int o = t & 127, s8 = t >> 7;       // 8 segments of 16 k each
        if (t < 128) mp[t] = part[(size_t)gg * 128 + t];
        __syncthreads();
        float p = 0.f;
#pragma unroll
        for (int q = 0; q < 16; ++q) { int k = s8 * 16 + q; p += mp[k] * Wf[(size_t)k * 128 + o]; }
        ps[t] = p;
        __syncthreads();
        if (t < 128) {
            float a = bfv[t];
#pragma unroll
            for (int q = 0; q < 8; ++q) a += ps[q * 128 + t];
            gl[t] = a;
        }
        __syncthreads();
        p = 0.f;
#pragma unroll
        for (int q = 0; q < 16; ++q) { int k = s8 * 16 + q; p += gl[k] * W2g[(size_t)(128 + k) * 128 + o]; }
        ps[t] = p;
        __syncthreads();
        if (t < 128) {
            float a = 0.f;
#pragma unroll
            for (int q = 0; q < 8; ++q) a += ps[q * 128 + t];
            gproj[(size_t)gg * 128 + t] = a;
        }
        return;
    }

    int g = blockIdx.x >> cshift;
    int c = blockIdx.x & ((1 << cshift) - 1);
    int gbase = g << 10;

    if (x) {
#pragma unroll
        for (int j = 0; j < 4; ++j) {
            int fl = j * 1024 + t;
            int v = fl >> 2, q = fl & 3;
            float dvv = rsqrtf((float)cnt[gbase + v] + 1.0f);
            float4 z = *(const float4*)&x[(size_t)(gbase + v) * FEAT + c * 16 + q * 4];
            z.x *= dvv; z.y *= dvv; z.z *= dvv; z.w *= dvv;
            sy4[fl] = z;
        }
    } else {
        const float4* Zg4 = (const float4*)(Z + ((size_t)c * NTOT + gbase) * 16);
#pragma unroll
        for (int j = 0; j < 4; ++j) sy4[j * 1024 + t] = Zg4[j * 1024 + t];
    }
    __syncthreads();

    int f4 = t & 3;
    int vl = t >> 2;                        // 0..255

#pragma unroll 1
    for (int pass = 0; pass < 4; ++pass) {
        int v = pass * 256 + vl;
        int gv = gbase + v;
        int n = cnt[gv];
        float dv = rsqrtf((float)n + 1.0f);
        const unsigned short* ip = col16 + gv;
        float4 acc = sy4[v * 4 + f4];       // self term
        int i = 0;
        if (n >= 4) {                        // software-pipelined: idx quad prefetched
            int a0 = ip[0];
            int a1 = ip[(size_t)1 * NTOT];
            int a2 = ip[(size_t)2 * NTOT];
            int a3 = ip[(size_t)3 * NTOT];
            for (; i + 8 <= n; i += 4) {
                int b0 = ip[(size_t)(i + 4) * NTOT];   // prefetch next group
                int b1 = ip[(size_t)(i + 5) * NTOT];
                int b2 = ip[(size_t)(i + 6) * NTOT];
                int b3 = ip[(size_t)(i + 7) * NTOT];
                float4 y0 = sy4[a0 * 4 + f4];          // consume current group
                float4 y1 = sy4[a1 * 4 + f4];
                float4 y2 = sy4[a2 * 4 + f4];
                float4 y3 = sy4[a3 * 4 + f4];
                acc.x += (y0.x + y1.x) + (y2.x + y3.x);
                acc.y += (y0.y + y1.y) + (y2.y + y3.y);
                acc.z += (y0.z + y1.z) + (y2.z + y3.z);
                acc.w += (y0.w + y1.w) + (y2.w + y3.w);
                a0 = b0; a1 = b1; a2 = b2; a3 = b3;
            }
            {   // drain the last prefetched group (covers i..i+3)
                float4 y0 = sy4[a0 * 4 + f4];
                float4 y1 = sy4[a1 * 4 + f4];
                float4 y2 = sy4[a2 * 4 + f4];
                float4 y3 = sy4[a3 * 4 + f4];
                acc.x += (y0.x + y1.x) + (y2.x + y3.x);
                acc.y += (y0.y + y1.y) + (y2.y + y3.y);
                acc.z += (y0.z + y1.z) + (y2.z + y3.z);
                acc.w += (y0.w + y1.w) + (y2.w + y3.w);
                i += 4;
            }
        }
        for (; i < n; ++i) {
            float4 ya = sy4[(int)ip[(size_t)i * NTOT] * 4 + f4];
            acc.x += ya.x; acc.y += ya.y; acc.z += ya.z; acc.w += ya.w;
        }
        acc.x *= dv; acc.y *= dv; acc.z *= dv; acc.w *= dv;
        // k-octet-major bf16 hi/lo write: plane = krow>>3, offset = krow&7 (0 or 4)
        int krow = c * 16 + f4 * 4;
        size_t ba = ((size_t)(krow >> 3) * NTOT + gv) * 8 + (krow & 7);
        ushort4 h, lo;
        h.x = f2bf(acc.x); lo.x = f2bf(acc.x - bf2f(h.x));
        h.y = f2bf(acc.y); lo.y = f2bf(acc.y - bf2f(h.y));
        h.z = f2bf(acc.z); lo.z = f2bf(acc.z - bf2f(h.z));
        h.w = f2bf(acc.w); lo.w = f2bf(acc.w - bf2f(h.w));
        *(ushort4*)&Ah[ba] = h;
        *(ushort4*)&Al[ba] = lo;
    }

    if (fvec && c == 0) {   // f_v = dinv_v*(dinv_v + sum dinv_s)
        __syncthreads();
        float* sdv = (float*)sy4;
        float dv = rsqrtf((float)cnt[gbase + t] + 1.0f);
        sdv[t] = dv;
        __syncthreads();
        int n = cnt[gbase + t];
        float acc = dv;
        const unsigned short* ip = col16 + gbase + t;
        for (int i = 0; i < n; ++i) acc += sdv[ip[(size_t)i * NTOT]];
        fvec[gbase + t] = dv * acc;
    }
}

// ---------------- bf16x3 MFMA GEMM: 64 rows x 128 cols per block, fused epilogue ----
// Single-shot A staging (whole K, 32 KB hi+lo, ONE barrier), B frags straight from L2
// (W small + shared by all blocks -> L2-hot broadcast; no LDS, no extra barriers).
// 4 waves; wave w owns cols w*32..w*32+31 (2x 16-col frags), all 64 rows (4x 16-row).
// A frag: row = lane&15, k-octet = lane>>4 (consistent A/B k-mapping => layout-safe).
// C/D frag (m89-verified): col = lane&15, row = (lane>>4)*4 + reg.
__global__ __launch_bounds__(256, 4) void gemm_k(const unsigned short* __restrict__ Ah,
                                                 const unsigned short* __restrict__ Al,
                                                 const unsigned short* __restrict__ Wph,
                                                 const unsigned short* __restrict__ Wpl,
                                                 const float* __restrict__ bias,
                                                 float* __restrict__ outZ,
                                                 int K,
                                                 const float* __restrict__ fvec,
                                                 const float* __restrict__ gproj,
                                                 float* __restrict__ part,
                                                 const float* __restrict__ W3,
                                                 const int* __restrict__ cnt,
                                                 float* __restrict__ zout) {
    __shared__ __align__(16) unsigned short sAh[64 * 128];   // [plane][row][8]  16 KB
    __shared__ __align__(16) unsigned short sAl[64 * 128];   // 16 KB
    __shared__ float zred[4 * 64];

    int t = threadIdx.x;
    int row0 = blockIdx.x * 64;
    int w = t >> 6;
    int l = t & 63;
    int lr = l & 15;
    int hg = l >> 4;

    f32x4 acc[4][2];
#pragma unroll
    for (int m = 0; m < 4; ++m)
#pragma unroll
        for (int n = 0; n < 2; ++n) acc[m][n] = (f32x4){0.f, 0.f, 0.f, 0.f};

    // stage ALL of A (K planes of [64 rows][8]) in one shot; per-thread nu uint4 pairs
    int nu = (K >> 3) << 6 >> 8;            // (K/8 planes * 64 rows) / 256 threads
    for (int i = 0; i < nu; ++i) {
        int u = t + i * 256;
        int p = u >> 6, r = u & 63;
        size_t src = ((size_t)p * NTOT + row0 + r) * 8;
        *(uint4*)&sAh[u * 8] = *(const uint4*)&Ah[src];
        *(uint4*)&sAl[u * 8] = *(const uint4*)&Al[src];
    }
    __syncthreads();                         // the ONLY pre-epilogue barrier

    int nk = K >> 5;
#pragma unroll 1
    for (int s = 0; s < nk; ++s) {
        int pb = s * 4 + hg;                 // this lane-group's k-plane
        bf16x8 ah[4], al[4], bh[2], bl[2];
#pragma unroll
        for (int m = 0; m < 4; ++m) {
            ah[m] = *(const bf16x8*)&sAh[(pb * 64 + m * 16 + lr) * 8];
            al[m] = *(const bf16x8*)&sAl[(pb * 64 + m * 16 + lr) * 8];
        }
#pragma unroll
        for (int n = 0; n < 2; ++n) {
            size_t wb = ((size_t)pb * 128 + w * 32 + n * 16 + lr) * 8;
            bh[n] = *(const bf16x8*)&Wph[wb];
            bl[n] = *(const bf16x8*)&Wpl[wb];
        }
#pragma unroll
        for (int m = 0; m < 4; ++m)
#pragma unroll
            for (int n = 0; n < 2; ++n) {
                acc[m][n] = __builtin_amdgcn_mfma_f32_16x16x32_bf16(ah[m], bh[n], acc[m][n], 0, 0, 0);
                acc[m][n] = __builtin_amdgcn_mfma_f32_16x16x32_bf16(al[m], bh[n], acc[m][n], 0, 0, 0);
                acc[m][n] = __builtin_amdgcn_mfma_f32_16x16x32_bf16(ah[m], bl[n], acc[m][n], 0, 0, 0);
            }
    }

    int g = row0 >> 10;
    int wc0 = w * 32;
    float bb[2], gp[2], w3c[2];
#pragma unroll
    for (int n = 0; n < 2; ++n) {
        int col = wc0 + n * 16 + lr;
        bb[n]  = bias[col];
        gp[n]  = fvec ? gproj[(size_t)g * 128 + col] : 0.f;
        w3c[n] = zout ? W3[col] : 0.f;
    }
    float fr[4][4];
    if (fvec) {
#pragma unroll
        for (int m = 0; m < 4; ++m)
#pragma unroll
            for (int r = 0; r < 4; ++r) fr[m][r] = fvec[row0 + m * 16 + hg * 4 + r];
    }
    float dvs[4][4];
    if (outZ) {
#pragma unroll
        for (int m = 0; m < 4; ++m)
#pragma unroll
            for (int r = 0; r < 4; ++r)
                dvs[m][r] = rsqrtf((float)cnt[row0 + m * 16 + hg * 4 + r] + 1.0f);
    }
    float zp[4][4];
#pragma unroll
    for (int m = 0; m < 4; ++m)
#pragma unroll
        for (int r = 0; r < 4; ++r) zp[m][r] = 0.f;
    float cmx[2] = {0.f, 0.f};

#pragma unroll
    for (int m = 0; m < 4; ++m)
#pragma unroll
        for (int n = 0; n < 2; ++n)
#pragma unroll
            for (int r = 0; r < 4; ++r) {
                float v = acc[m][n][r] + bb[n];
                if (fvec) v += fr[m][r] * gp[n];
                v = fmaxf(v, 0.f);
                if (part) cmx[n] = fmaxf(cmx[n], v);
                if (zout) zp[m][r] += v * w3c[n];
                if (outZ) {
                    int row = row0 + m * 16 + hg * 4 + r;
                    int cidx = w * 2 + n;
                    outZ[((size_t)cidx * NTOT + row) * 16 + lr] = v * dvs[m][r];
                }
            }

    if (part) {   // per-graph col-max: reduce across the wave's 64 rows, then atomicMax
#pragma unroll
        for (int n = 0; n < 2; ++n) {
            float v = cmx[n];
            v = fmaxf(v, __shfl_xor(v, 16));
            v = fmaxf(v, __shfl_xor(v, 32));
            if (hg == 0)
                atomicMax((int*)&part[(size_t)g * 128 + wc0 + n * 16 + lr],
                          __float_as_int(v));
        }
    }

    if (zout) {   // reduce row-dots across 16 col-lanes, then across 4 waves via LDS
#pragma unroll
        for (int m = 0; m < 4; ++m)
#pragma unroll
            for (int r = 0; r < 4; ++r) {
                float v = zp[m][r];
                v += __shfl_xor(v, 1);
                v += __shfl_xor(v, 2);
                v += __shfl_xor(v, 4);
                v += __shfl_xor(v, 8);
                zp[m][r] = v;
            }
        if (lr == 0) {
#pragma unroll
            for (int m = 0; m < 4; ++m)
#pragma unroll
                for (int r = 0; r < 4; ++r)
                    zred[w * 64 + m * 16 + hg * 4 + r] = zp[m][r];
        }
        __syncthreads();
        if (t < 64) {
            float sZ = zred[t] + zred[64 + t] + zred[128 + t] + zred[192 + t];
            zout[row0 + t] = sZ * rsqrtf((float)cnt[row0 + t] + 1.0f);
        }
    }
}

// ---------------- fused scalar-agg + top-K mask (one block per graph, 1024 thr) ------
// one node per thread; top-K knockout via wave shfl_xor argmax + 16-entry combine.
__global__ __launch_bounds__(1024) void smask_k(const float* __restrict__ z,
                                                const unsigned short* __restrict__ col16,
                                                const int* __restrict__ cnt,
                                                const float* __restrict__ b3,
                                                float* __restrict__ out) {
    __shared__ float sz[1024];
    __shared__ float sl[1024];
    __shared__ float slo[1024];
    __shared__ float rv[16];
    __shared__ int   ri[16];
    __shared__ float sth;
    int g = blockIdx.x, t = threadIdx.x;
    int wv = t >> 6, ln = t & 63;
    int base = g << 10;
    sz[t] = z[base + t];
    __syncthreads();
    float bb = b3[0];
    {
        int gv = base + t;
        int n = cnt[gv];
        float dv = rsqrtf((float)n + 1.0f);
        float acc = sz[t];
        const unsigned short* ip = col16 + gv;   // slot-major, coalesced
        int j = 0;
        for (; j + 2 <= n; j += 2)
            acc += sz[ip[(size_t)j * NTOT]] + sz[ip[(size_t)(j + 1) * NTOT]];
        for (; j < n; ++j) acc += sz[ip[(size_t)j * NTOT]];
        float lg = acc * dv + bb;
        sl[t] = lg; slo[t] = lg;
    }
    __syncthreads();
    for (int pass = 0; pass < KSEL; ++pass) {
        float bv = sl[t];
        int bi = t;
#pragma unroll
        for (int off = 32; off; off >>= 1) {   // wave argmax, deterministic tie-break
            float ov = __shfl_xor(bv, off);
            int   oi = __shfl_xor(bi, off);
            if (ov > bv || (ov == bv && oi < bi)) { bv = ov; bi = oi; }
        }
        if (ln == 0) { rv[wv] = bv; ri[wv] = bi; }
        __syncthreads();
        if (t == 0) {
            float mv = rv[0]; int mi = ri[0];
#pragma unroll
            for (int q = 1; q < 16; ++q)
                if (rv[q] > mv || (rv[q] == mv && ri[q] < mi)) { mv = rv[q]; mi = ri[q]; }
            sth = mv; sl[mi] = -INFINITY;
        }
        __syncthreads();
    }
    float th = sth;
    out[base + t] = (slo[t] >= th) ? 1.f : 0.f;
}

// =====================================================================================
extern "C" void kernel_launch(void* const* d_in, const int* in_sizes, int n_in,
                              void* d_out, int out_size, void* d_ws, size_t ws_size,
                              hipStream_t stream) {
    const float* x        = (const float*)d_in[0];
    const int*   edge_src = (const int*)d_in[1];
    const int*   edge_dst = (const int*)d_in[2];
    const float* W0 = (const float*)d_in[4];
    const float* b0 = (const float*)d_in[5];
    const float* W1 = (const float*)d_in[6];
    const float* b1 = (const float*)d_in[7];
    const float* Wf = (const float*)d_in[8];
    const float* bf = (const float*)d_in[9];
    const float* W2 = (const float*)d_in[10];
    const float* b2 = (const float*)d_in[11];
    const float* W3 = (const float*)d_in[12];
    const float* b3 = (const float*)d_in[13];
    float* out = (float*)d_out;

    char* w = (char*)d_ws;
    int*            cnt   = (int*)w;            w += (size_t)NTOT * 4;
    unsigned short* col16 = (unsigned short*)w; w += (size_t)NTOT * MAXDEG * 2;
    float*          fvec  = (float*)w;          w += (size_t)NTOT * 4;
    unsigned short* Ah    = (unsigned short*)w; w += (size_t)NTOT * 128 * 2;  // A hi
    unsigned short* Al    = (unsigned short*)w; w += (size_t)NTOT * 128 * 2;  // A lo
    float*          Q     = (float*)w;          w += (size_t)NTOT * 128 * 4;  // Z
    float*          part  = (float*)w;          w += (size_t)NB * 128 * 4;
    float*          gproj = (float*)w;          w += (size_t)NB * 128 * 4;
    float*          z     = (float*)w;          w += (size_t)NTOT * 4;
    unsigned short* Wph   = (unsigned short*)w; w += (size_t)320 * 128 * 2;   // packed W hi
    unsigned short* Wpl   = (unsigned short*)w; w += (size_t)320 * 128 * 2;   // packed W lo

    // csr (per-graph, LDS atomics; slot-major col16) + pack + part-zero, one dispatch
    csrpack_k<<<NB + 41, 1024, 0, stream>>>(edge_src, edge_dst, cnt, col16,
                                            W0, W1, W2, Wph, Wpl, part);

    // conv0: A = agg(x) [K=64]; Z0 = relu(A@W0+b0)*dinv, fused maxpool -> part
    agg_k<<<NB * 4, 1024, 0, stream>>>(nullptr, x, col16, cnt, Ah, Al, 2, nullptr,
                                       nullptr, nullptr, nullptr, nullptr, nullptr);
    gemm_k<<<NTOT / 64, 256, 0, stream>>>(Ah, Al, Wph, Wpl, b0, Q, FEAT,
                                          nullptr, nullptr, part, nullptr, cnt, nullptr);

    // conv1 twice (same weights); first agg also carries the NB glob blocks
    agg_k<<<NB * 8 + NB, 1024, 0, stream>>>(Q, nullptr, col16, cnt, Ah, Al, 3, nullptr,
                                            Wf, bf, W2, gproj, part);
    gemm_k<<<NTOT / 64, 256, 0, stream>>>(Ah, Al, Wph + 64 * 128, Wpl + 64 * 128, b1, Q,
                                          HID, nullptr, nullptr, nullptr, nullptr, cnt,
                                          nullptr);
    agg_k<<<NB * 8, 1024, 0, stream>>>(Q, nullptr, col16, cnt, Ah, Al, 3, nullptr,
                                       nullptr, nullptr, nullptr, nullptr, nullptr);
    gemm_k<<<NTOT / 64, 256, 0, stream>>>(Ah, Al, Wph + 64 * 128, Wpl + 64 * 128, b1, Q,
                                          HID, nullptr, nullptr, nullptr, nullptr, cnt,
                                          nullptr);

    // conv2: A = agg(Z2) (+fvec); z = dinv*(relu(A@W2a + f*gproj + b2)@W3)
    agg_k<<<NB * 8, 1024, 0, stream>>>(Q, nullptr, col16, cnt, Ah, Al, 3, fvec,
                                       nullptr, nullptr, nullptr, nullptr, nullptr);
    gemm_k<<<NTOT / 64, 256, 0, stream>>>(Ah, Al, Wph + 192 * 128, Wpl + 192 * 128, b2,
                                          nullptr, HID, fvec, gproj, nullptr, W3, cnt, z);

    // logits = agg_scalar(z) + b3, then per-graph top-10 mask (fused)
    smask_k<<<NB, 1024, 0, stream>>>(z, col16, cnt, b3, out);
}